// Round 1
// baseline (111.404 us; speedup 1.0000x reference)
//
#include <hip/hip_runtime.h>

// RBF kernel: out[n,m] = exp(-0.5 * sum_d (x[n,d]-c[m,d])^2 / s2[m,d]) / sqrt((2pi)^D * prod_d s2[m,d])
// Decomposition: sum (x-c)^2 w = sum x^2 w - 2 sum x (c w) + sum c^2 w   (w = 1/s2)
// Folded epilogue: out = exp2( L2E*S2 - 0.5*L2E*S1 + c0 ),
//   c0 = -0.5*L2E*sum(c^2 w) - 0.5*(D*log2(2pi) + sum log2(s2))

#define N_  16384
#define M_  1024
#define D_  32
#define NT  64      // n-rows per block
#define BLK 256     // threads per block = m-tile width

__global__ __launch_bounds__(BLK) void rbf_kernel(
    const float* __restrict__ x, const float* __restrict__ centers,
    const float* __restrict__ sigma, float* __restrict__ out)
{
    const int tid = threadIdx.x;
    const int m   = blockIdx.x * BLK + tid;   // M = 4 * 256, exact
    const int n0  = blockIdx.y * NT;          // N = 256 * 64, exact

    // x tile + squared x tile, staged once per block. Reads in the hot loop
    // are wave-uniform addresses -> LDS broadcast (conflict-free).
    __shared__ float4 xs4 [NT * D_ / 4];   // 8 KB
    __shared__ float4 x2s4[NT * D_ / 4];   // 8 KB

    {
        const float4* xg = (const float4*)(x + (size_t)n0 * D_);
        #pragma unroll
        for (int i = tid; i < NT * D_ / 4; i += BLK) {
            float4 v = xg[i];                         // coalesced 16B/lane
            xs4[i]  = v;
            x2s4[i] = make_float4(v.x * v.x, v.y * v.y, v.z * v.z, v.w * v.w);
        }
    }

    // Per-m precompute, all in registers (constant indices after unroll).
    // With sigma == 1 this is exact: w = 1, a = c, ld = 0.
    float w[D_], a[D_];
    float b = 0.0f, ld = 0.0f;
    #pragma unroll
    for (int d = 0; d < D_; ++d) {
        float s  = sigma[(size_t)m * D_ + d];
        float c  = centers[(size_t)m * D_ + d];
        float s2 = s * s;
        float wi = 1.0f / s2;
        float ai = c * wi;
        w[d] = wi;
        a[d] = ai;
        b  = fmaf(c, ai, b);
        ld += log2f(s2);
    }
    const float L2E = 1.4426950408889634f;        // log2(e)
    const float LOG2_2PI = 2.6514961294723187f;   // log2(2*pi)
    const float c0 = fmaf(-0.5f * L2E, b, -0.5f * (D_ * LOG2_2PI + ld));

    __syncthreads();

    for (int i = 0; i < NT; ++i) {
        const float4* xr  = &xs4 [i * (D_ / 4)];
        const float4* x2r = &x2s4[i * (D_ / 4)];
        float s1a = 0.f, s1b = 0.f, s2a = 0.f, s2b = 0.f;
        #pragma unroll
        for (int k = 0; k < D_ / 4; ++k) {
            float4 xv = xr[k];    // ds_read_b128, broadcast
            float4 q  = x2r[k];
            s2a = fmaf(xv.x, a[4*k+0], s2a);
            s2b = fmaf(xv.y, a[4*k+1], s2b);
            s2a = fmaf(xv.z, a[4*k+2], s2a);
            s2b = fmaf(xv.w, a[4*k+3], s2b);
            s1a = fmaf(q.x,  w[4*k+0], s1a);
            s1b = fmaf(q.y,  w[4*k+1], s1b);
            s1a = fmaf(q.z,  w[4*k+2], s1a);
            s1b = fmaf(q.w,  w[4*k+3], s1b);
        }
        float S1 = s1a + s1b;
        float S2 = s2a + s2b;
        float f  = fmaf(L2E, S2, fmaf(-0.5f * L2E, S1, c0));
        out[(size_t)(n0 + i) * M_ + m] = __builtin_amdgcn_exp2f(f);  // coalesced store
    }
}

extern "C" void kernel_launch(void* const* d_in, const int* in_sizes, int n_in,
                              void* d_out, int out_size, void* d_ws, size_t ws_size,
                              hipStream_t stream) {
    const float* x = (const float*)d_in[0];
    const float* c = (const float*)d_in[1];
    const float* s = (const float*)d_in[2];
    float* out = (float*)d_out;
    dim3 grid(M_ / BLK, N_ / NT);
    rbf_kernel<<<grid, BLK, 0, stream>>>(x, c, s, out);
}

// Round 2
// 96.050 us; speedup vs baseline: 1.1598x; 1.1598x over previous
//
#include <hip/hip_runtime.h>

// out[n,m] = exp(-0.5 * sum_d (x[n,d]-c[m,d])^2 / s2[m,d]) / sqrt((2pi)^D * prod_d s2[m,d])
//
// Fast path (sigma uniform across d for every lane in the wave, true for the bench):
//   X = w0*r2[n] - 2*sum_d x*a_d + sum_d c*a_d,   a = c*w0,  r2[n] = sum_d x^2
//   out = exp2( L2E*S2 + q*r2[n] + c0 ),  q = -0.5*L2E*w0
// x rows are wave-uniform -> loaded via SMEM (s_load), not LDS. Inner loop is
// 16x float2 fma (v_pk_fma_f32-packable), no LDS traffic except 1 ds_read_b32/row.

#define N_  16384
#define M_  1024
#define D_  32
#define NT  64      // n-rows per block
#define BLK 256     // threads per block = m-tile width

typedef float v2f __attribute__((ext_vector_type(2)));

__global__ __launch_bounds__(BLK) void rbf_kernel(
    const float* __restrict__ x, const float* __restrict__ centers,
    const float* __restrict__ sigma, float* __restrict__ out)
{
    const int tid = threadIdx.x;
    const int m   = blockIdx.x * BLK + tid;   // M = 4 * 256, exact
    const int n0  = blockIdx.y * NT;          // N = 256 * 64, exact

    __shared__ float r2s[NT];   // 256 B

    // Stage r2[row] = sum_d x[row,d]^2 (consumed by the fast path).
    if (tid < NT) {
        const float4* xr = (const float4*)(x + (size_t)(n0 + tid) * D_);
        float a0 = 0.f, a1 = 0.f, a2 = 0.f, a3 = 0.f;
        #pragma unroll
        for (int k = 0; k < D_ / 4; ++k) {
            float4 v = xr[k];
            a0 = fmaf(v.x, v.x, a0); a1 = fmaf(v.y, v.y, a1);
            a2 = fmaf(v.z, v.z, a2); a3 = fmaf(v.w, v.w, a3);
        }
        r2s[tid] = (a0 + a1) + (a2 + a3);
    }
    __syncthreads();   // single barrier, before any divergent path

    const float L2E      = 1.4426950408889634f;   // log2(e)
    const float LOG2_2PI = 2.6514961294723187f;   // log2(2*pi)

    // sigma pass: per-thread check "variance uniform across d" + log-determinant
    float s2_0 = 0.f, ld = 0.f;
    bool uf = true;
    {
        const float* sg = sigma + (size_t)m * D_;
        #pragma unroll
        for (int d = 0; d < D_; ++d) {
            float s  = sg[d];
            float s2 = s * s;
            if (d == 0) s2_0 = s2;
            uf = uf && (s2 == s2_0);
            ld += log2f(s2);               // exactly 0 when s2 == 1
        }
    }

    if (__all((int)uf)) {
        // ---- fast path: S1 = w0 * r2[row] ----
        const float w0 = 1.0f / s2_0;
        v2f av[D_ / 2];
        float b = 0.f;
        {
            const v2f* cg = (const v2f*)(centers + (size_t)m * D_);
            #pragma unroll
            for (int j = 0; j < D_ / 2; ++j) {
                v2f c = cg[j];
                v2f a = c * w0;
                av[j] = a;
                b = fmaf(c.x, a.x, b);
                b = fmaf(c.y, a.y, b);
            }
        }
        const float c0 = fmaf(-0.5f * L2E, b, -0.5f * (D_ * LOG2_2PI + ld));
        const float q  = -0.5f * L2E * w0;

        for (int i = 0; i < NT; ++i) {
            // loop-uniform address -> scalar (SMEM) loads, zero VALU/LDS cost
            const v2f* xr = (const v2f*)(x + (size_t)(n0 + i) * D_);
            v2f acc0 = {0.f, 0.f}, acc1 = {0.f, 0.f};
            v2f acc2 = {0.f, 0.f}, acc3 = {0.f, 0.f};
            #pragma unroll
            for (int j = 0; j < D_ / 2; j += 4) {
                acc0 += xr[j + 0] * av[j + 0];   // v_pk_fma_f32, SGPR-pair src
                acc1 += xr[j + 1] * av[j + 1];
                acc2 += xr[j + 2] * av[j + 2];
                acc3 += xr[j + 3] * av[j + 3];
            }
            v2f s = (acc0 + acc1) + (acc2 + acc3);
            float S2 = s.x + s.y;
            float f  = fmaf(L2E, S2, fmaf(q, r2s[i], c0));
            out[(size_t)(n0 + i) * M_ + m] = __builtin_amdgcn_exp2f(f);  // coalesced
        }
    } else {
        // ---- general path: direct sum_d w_d (x-c)^2, still SMEM x loads ----
        float wv[D_], cv[D_];
        {
            const float* sg = sigma   + (size_t)m * D_;
            const float* cg = centers + (size_t)m * D_;
            #pragma unroll
            for (int d = 0; d < D_; ++d) {
                float s = sg[d];
                wv[d] = 1.0f / (s * s);
                cv[d] = cg[d];
            }
        }
        const float c0 = -0.5f * (D_ * LOG2_2PI + ld);
        for (int i = 0; i < NT; ++i) {
            const float* xr = x + (size_t)(n0 + i) * D_;
            float a0 = 0.f, a1 = 0.f;
            #pragma unroll
            for (int d = 0; d < D_; d += 2) {
                float t0 = xr[d]     - cv[d];
                float t1 = xr[d + 1] - cv[d + 1];
                a0 = fmaf(t0 * wv[d],     t0, a0);
                a1 = fmaf(t1 * wv[d + 1], t1, a1);
            }
            float X = a0 + a1;
            float f = fmaf(-0.5f * L2E, X, c0);
            out[(size_t)(n0 + i) * M_ + m] = __builtin_amdgcn_exp2f(f);
        }
    }
}

extern "C" void kernel_launch(void* const* d_in, const int* in_sizes, int n_in,
                              void* d_out, int out_size, void* d_ws, size_t ws_size,
                              hipStream_t stream) {
    const float* x = (const float*)d_in[0];
    const float* c = (const float*)d_in[1];
    const float* s = (const float*)d_in[2];
    float* out = (float*)d_out;
    dim3 grid(M_ / BLK, N_ / NT);
    rbf_kernel<<<grid, BLK, 0, stream>>>(x, c, s, out);
}